// Round 11
// baseline (101.544 us; speedup 1.0000x reference)
//
#include <hip/hip_runtime.h>
#include <hip/hip_fp16.h>
#include <math.h>

// Capsule routing, fused, packed-fp16, register-carried exp, register-cached W.
// Single kernel (convert_w eliminated): each thread loads its 16 fp32 W rows
// once, converts to 32 h2 VGPRs; bias to 8 f32. 640 thr/block:
// thread = (j = wave 0..9, dhalf = bit5, ns = lane&31).
// Key identity: thread (j,dhalf,ns) needs, in phase B of iter it+1, exactly
// the e = exp(ua·x) it computed in phase E of iter it -> carried in 9 h2 regs
// (ereg). LDS e copy (eJ) exists ONLY for A''s denominator.
// Per iter: B (c = ereg*sinv, t2 += c*x) -> C (ps = W·t, butterfly over ns)
// -> D (u = v·W, ua += u) -> E (ereg = exp(ua·x), store eJ) -> barrier ->
// A' (sinv2 = 1/sum_j eJ) -> barrier.
// Bank layouts (all conflict-free): xs 8-half rows b128; eJ lane-stride-1 h2;
// sinv2 [pr][2ns+s] f32 b64.
// Softmax without max-subtraction: |b| <~ 5, exp safe in f32 (validated R7).
// __launch_bounds__(640,2): 20 waves/CU -> 102-VGPR ceiling; measured usage
// ~64 before W-caching, ~95 expected now. (2nd arg >=5 clamps to 48 VGPR ->
// R4/R5 spill cascade; keep 2.) iter-0 cs = 1.8 per half (pair-merge doubles
// to 3.6) - R8's bug.

#define BSZ   512
#define C_IN  256
#define HW    36
#define NS    32
#define NOC   10
#define OD    16
#define ROUTE 3
#define NIC   1152
#define NT    640

typedef __half2 h2;

__device__ __forceinline__ h2 u2h(unsigned int v) {
    union { unsigned int u; h2 h; } x; x.u = v; return x.h;
}
__device__ __forceinline__ h2 shflx_h2(h2 v, int m) {
    union { h2 h; int i; } x; x.h = v; x.i = __shfl_xor(x.i, m); return x.h;
}

__global__ __launch_bounds__(NT, 2) void caps_kernel(
    const float* __restrict__ x,    // [BSZ, 256, 36] fp32
    const float* __restrict__ Wc,   // [5120, 8] fp32
    const float* __restrict__ bc,   // [5120] fp32
    float* __restrict__ out)        // [BSZ, 10, 16] fp32
{
    __shared__ h2    xs[NIC * 4];          // 18432 B: row i=p*32+ns, 8 halfs
    __shared__ h2    eJ[NOC * 18 * 32];    // 23040 B: e pairs, (j*18+pr)*32+ns
    __shared__ float sinv2[NIC];           //  4608 B: 1/denom, pr*64 + ns*2 + s
    // total 46080 B -> 2 blocks/CU

    const int tid = threadIdx.x;
    const float* xb = x + (size_t)blockIdx.x * (C_IN * HW);

    // ---- Stage x -> fp16 LDS row-major (conflict-free; validated R7/R9) ----
    for (int t5 = tid; t5 < 9 * 128; t5 += NT) {
        int p4 = t5 >> 7, c2 = t5 & 127;
        int nsc = c2 >> 2, k2 = c2 & 3;
        const float* s0 = xb + (2 * c2) * HW + p4 * 4;
        float4 a = *(const float4*)s0;
        float4 b = *(const float4*)(s0 + HW);
        xs[((p4 * 4 + 0) * 32 + nsc) * 4 + k2] = __floats2half2_rn(a.x, b.x);
        xs[((p4 * 4 + 1) * 32 + nsc) * 4 + k2] = __floats2half2_rn(a.y, b.y);
        xs[((p4 * 4 + 2) * 32 + nsc) * 4 + k2] = __floats2half2_rn(a.z, b.z);
        xs[((p4 * 4 + 3) * 32 + nsc) * 4 + k2] = __floats2half2_rn(a.w, b.w);
    }

    const int j     = tid >> 6;         // 0..9 (= wave index)
    const int dhalf = (tid >> 5) & 1;   // which 8 of the 16 out-dims
    const int ns    = tid & 31;

    // ---- One-time: W rows (own 8 d's x 8 k) fp32 -> 32 h2 regs; bias -> f32 ----
    h2    wreg[32];
    float bcv[8];
    {
        const float* wp = Wc + (size_t)(ns * 160 + j * 16 + dhalf * 8) * 8;
        #pragma unroll
        for (int dd = 0; dd < 8; ++dd) {
            float4 a = *(const float4*)(wp + dd * 8);
            float4 b = *(const float4*)(wp + dd * 8 + 4);
            wreg[dd * 4 + 0] = __floats2half2_rn(a.x, a.y);
            wreg[dd * 4 + 1] = __floats2half2_rn(a.z, a.w);
            wreg[dd * 4 + 2] = __floats2half2_rn(b.x, b.y);
            wreg[dd * 4 + 3] = __floats2half2_rn(b.z, b.w);
        }
        const float* bp = bc + ns * 160 + j * 16 + dhalf * 8;
        float4 b0 = *(const float4*)bp;
        float4 b1 = *(const float4*)(bp + 4);
        bcv[0]=b0.x; bcv[1]=b0.y; bcv[2]=b0.z; bcv[3]=b0.w;
        bcv[4]=b1.x; bcv[5]=b1.y; bcv[6]=b1.z; bcv[7]=b1.w;
    }
    __syncthreads();

    const int q0 = dhalf * 9;   // own p-pairs pr = q0..q0+8
    float ua[9];                // cumulative routing coefficients (f32 canonical)
    h2    ua2[4];               // packed mirror for the fp16 dots
    h2    ereg[9];              // e = exp(b) for own (j, p-pairs), carried E->B

    for (int it = 0; it < ROUTE; ++it) {
        // ---- Phase B: t2[k2] = sum_p c*x2, tc = sum_p c (own 18 p) ----
        h2 t2[4];
        h2 zz = __float2half2_rn(0.f);
        t2[0] = zz; t2[1] = zz; t2[2] = zz; t2[3] = zz;
        float tc = 0.f;
        if (it == 0) {
            #pragma unroll
            for (int q = 0; q < 9; ++q) {
                #pragma unroll
                for (int s = 0; s < 2; ++s) {
                    int row = (2 * (q0 + q) + s) * 32 + ns;
                    uint4 xv = *(const uint4*)&xs[row * 4];
                    t2[0] = __hadd2(t2[0], u2h(xv.x));
                    t2[1] = __hadd2(t2[1], u2h(xv.y));
                    t2[2] = __hadd2(t2[2], u2h(xv.z));
                    t2[3] = __hadd2(t2[3], u2h(xv.w));
                }
            }
            h2 tenth = __float2half2_rn(0.1f);
            #pragma unroll
            for (int k = 0; k < 4; ++k) t2[k] = __hmul2(t2[k], tenth);
            tc = 1.8f;   // per-half; pair merge below doubles to 3.6 (= sum_p 0.1)
        } else {
            #pragma unroll
            for (int q = 0; q < 9; ++q) {
                int pr = q0 + q;
                float2 sv = *(const float2*)&sinv2[pr * 64 + ns * 2];
                float2 ef = __half22float2(ereg[q]);
                float c0 = ef.x * sv.x;
                float c1 = ef.y * sv.y;
                tc += c0 + c1;
                h2 c20 = __float2half2_rn(c0);
                h2 c21 = __float2half2_rn(c1);
                {
                    uint4 xv = *(const uint4*)&xs[((2 * pr + 0) * 32 + ns) * 4];
                    t2[0] = __hfma2(c20, u2h(xv.x), t2[0]);
                    t2[1] = __hfma2(c20, u2h(xv.y), t2[1]);
                    t2[2] = __hfma2(c20, u2h(xv.z), t2[2]);
                    t2[3] = __hfma2(c20, u2h(xv.w), t2[3]);
                }
                {
                    uint4 xv = *(const uint4*)&xs[((2 * pr + 1) * 32 + ns) * 4];
                    t2[0] = __hfma2(c21, u2h(xv.x), t2[0]);
                    t2[1] = __hfma2(c21, u2h(xv.y), t2[1]);
                    t2[2] = __hfma2(c21, u2h(xv.z), t2[2]);
                    t2[3] = __hfma2(c21, u2h(xv.w), t2[3]);
                }
            }
        }
        // merge dhalf pair (both halves then hold full-p t)
        #pragma unroll
        for (int k = 0; k < 4; ++k) t2[k] = __hadd2(t2[k], shflx_h2(t2[k], 32));
        tc += __shfl_xor(tc, 32);

        // ---- Phase C: ps[dd] = W·t + bcv*tc (own 8 d); butterfly over ns ----
        float ps[8];
        #pragma unroll
        for (int dd = 0; dd < 8; ++dd) {
            h2 a = __hmul2(wreg[dd * 4 + 0], t2[0]);
            a = __hfma2(wreg[dd * 4 + 1], t2[1], a);
            a = __hfma2(wreg[dd * 4 + 2], t2[2], a);
            a = __hfma2(wreg[dd * 4 + 3], t2[3], a);
            float2 f = __half22float2(a);
            ps[dd] = f.x + f.y + bcv[dd] * tc;
        }
        #pragma unroll
        for (int mk = 1; mk < 32; mk <<= 1) {
            #pragma unroll
            for (int dd = 0; dd < 8; ++dd)
                ps[dd] += __shfl_xor(ps[dd], mk);
        }
        float ssp = 0.f;
        #pragma unroll
        for (int dd = 0; dd < 8; ++dd) ssp += ps[dd] * ps[dd];
        float ss = ssp + __shfl_xor(ssp, 32);
        float fc = sqrtf(ss) / (1.f + ss);

        if (it == ROUTE - 1) {
            if (ns == 0) {
                float* o = out + (size_t)blockIdx.x * (NOC * OD) + j * OD + dhalf * 8;
                *(float4*)o       = make_float4(ps[0]*fc, ps[1]*fc, ps[2]*fc, ps[3]*fc);
                *(float4*)(o + 4) = make_float4(ps[4]*fc, ps[5]*fc, ps[6]*fc, ps[7]*fc);
            }
            break;
        }

        // ---- Phase D: u2[k2] = sum_d v_d*W2[d,k2] (own 8 d); merge; ua += ----
        h2 u2[4];
        u2[0] = zz; u2[1] = zz; u2[2] = zz; u2[3] = zz;
        float u8 = 0.f;
        #pragma unroll
        for (int dd = 0; dd < 8; ++dd) {
            float vv = ps[dd] * fc;
            h2 v2 = __float2half2_rn(vv);
            u2[0] = __hfma2(v2, wreg[dd * 4 + 0], u2[0]);
            u2[1] = __hfma2(v2, wreg[dd * 4 + 1], u2[1]);
            u2[2] = __hfma2(v2, wreg[dd * 4 + 2], u2[2]);
            u2[3] = __hfma2(v2, wreg[dd * 4 + 3], u2[3]);
            u8 += vv * bcv[dd];
        }
        #pragma unroll
        for (int k = 0; k < 4; ++k) u2[k] = __hadd2(u2[k], shflx_h2(u2[k], 32));
        u8 += __shfl_xor(u8, 32);
        {
            float2 f0 = __half22float2(u2[0]);
            float2 f1 = __half22float2(u2[1]);
            float2 f2 = __half22float2(u2[2]);
            float2 f3 = __half22float2(u2[3]);
            if (it == 0) {
                ua[0]=f0.x; ua[1]=f0.y; ua[2]=f1.x; ua[3]=f1.y;
                ua[4]=f2.x; ua[5]=f2.y; ua[6]=f3.x; ua[7]=f3.y; ua[8]=u8;
            } else {
                ua[0]+=f0.x; ua[1]+=f0.y; ua[2]+=f1.x; ua[3]+=f1.y;
                ua[4]+=f2.x; ua[5]+=f2.y; ua[6]+=f3.x; ua[7]+=f3.y; ua[8]+=u8;
            }
            ua2[0] = __floats2half2_rn(ua[0], ua[1]);
            ua2[1] = __floats2half2_rn(ua[2], ua[3]);
            ua2[2] = __floats2half2_rn(ua[4], ua[5]);
            ua2[3] = __floats2half2_rn(ua[6], ua[7]);
        }

        // ---- Phase E: ereg[q] = exp(ua·(x,1)) pairs; store to eJ for A' ----
        #pragma unroll
        for (int q = 0; q < 9; ++q) {
            int pr = q0 + q;
            float eb[2];
            #pragma unroll
            for (int s = 0; s < 2; ++s) {
                int row = (2 * pr + s) * 32 + ns;
                uint4 xv = *(const uint4*)&xs[row * 4];
                h2 a = __hmul2(ua2[0], u2h(xv.x));
                a = __hfma2(ua2[1], u2h(xv.y), a);
                a = __hfma2(ua2[2], u2h(xv.z), a);
                a = __hfma2(ua2[3], u2h(xv.w), a);
                float2 af = __half22float2(a);
                eb[s] = __expf(ua[8] + af.x + af.y);
            }
            ereg[q] = __floats2half2_rn(eb[0], eb[1]);
            eJ[(j * 18 + pr) * 32 + ns] = ereg[q];
        }
        __syncthreads();

        // ---- Phase A': sinv2 = 1/sum_j e  (576 pair-tasks, stride-1 banks) ----
        if (tid < 576) {
            int pr = tid >> 5, a = tid & 31;
            h2 s2 = eJ[pr * 32 + a];
            #pragma unroll
            for (int jj = 1; jj < NOC; ++jj)
                s2 = __hadd2(s2, eJ[(jj * 18 + pr) * 32 + a]);
            float2 sf = __half22float2(s2);
            *(float2*)&sinv2[pr * 64 + a * 2] =
                make_float2(__frcp_rn(sf.x), __frcp_rn(sf.y));
        }
        __syncthreads();
    }
}

extern "C" void kernel_launch(void* const* d_in, const int* in_sizes, int n_in,
                              void* d_out, int out_size, void* d_ws, size_t ws_size,
                              hipStream_t stream) {
    const float* x  = (const float*)d_in[0];
    // d_in[1] = target (int32) — unused in forward
    const float* Wc = (const float*)d_in[2];
    const float* bc = (const float*)d_in[3];
    float* out = (float*)d_out;

    caps_kernel<<<dim3(BSZ), dim3(NT), 0, stream>>>(x, Wc, bc, out);
}

// Round 12
// 99.864 us; speedup vs baseline: 1.0168x; 1.0168x over previous
//
#include <hip/hip_runtime.h>
#include <hip/hip_fp16.h>
#include <math.h>

// Capsule routing, fused, packed-fp16, register-carried exp, register-cached W,
// DPP reductions. 640 thr/block: thread = (j = wave 0..9, dhalf = bit5,
// ns = lane&31).
// Reductions over ns: masks 1,2,4,8 via DPP row_ror rotate-accumulate (VALU
// pipe, ~2cyc) + one shfl_xor(16) (DS) -> phase C drops from 40 to 8 DS ops.
// sinv stored fp16 h2 lane-stride-1 (b32 reads). e carried E->B in 9 h2 regs;
// eJ LDS copy exists only for A''s denominator. W cached in 32 h2 VGPRs.
// Per iter: B (c = ereg*sinv, t2 += c*x) -> C (ps = W·t, DPP+shfl reduce) ->
// D (u = v·W, ua += u) -> E (ereg = exp(ua·x), store eJ) -> barrier ->
// A' (sinvH = 1/sum_j eJ) -> barrier.
// Softmax without max-subtraction: |b| <~ 5, exp safe in f32 (validated R7).
// __launch_bounds__(640,2): ~102-VGPR ceiling at 5 waves/EU; 2nd arg >=5
// clamps to 48 VGPR (R4/R5 spill cascade) - keep 2. iter-0 cs = 1.8 per half
// (pair merge doubles to 3.6) - R8's bug.

#define BSZ   512
#define C_IN  256
#define HW    36
#define NS    32
#define NOC   10
#define OD    16
#define ROUTE 3
#define NIC   1152
#define NT    640

typedef __half2 h2;

__device__ __forceinline__ h2 u2h(unsigned int v) {
    union { unsigned int u; h2 h; } x; x.u = v; return x.h;
}
__device__ __forceinline__ h2 shflx_h2(h2 v, int m) {
    union { h2 h; int i; } x; x.h = v; x.i = __shfl_xor(x.i, m); return x.h;
}
// Sum over the 16-lane DPP row via rotate-accumulate (VALU pipe, no LDS).
__device__ __forceinline__ float row16_sum(float v) {
    int t;
    t = __builtin_amdgcn_update_dpp(0, __float_as_int(v), 0x121, 0xF, 0xF, true);
    v += __int_as_float(t);   // ror 1
    t = __builtin_amdgcn_update_dpp(0, __float_as_int(v), 0x122, 0xF, 0xF, true);
    v += __int_as_float(t);   // ror 2
    t = __builtin_amdgcn_update_dpp(0, __float_as_int(v), 0x124, 0xF, 0xF, true);
    v += __int_as_float(t);   // ror 4
    t = __builtin_amdgcn_update_dpp(0, __float_as_int(v), 0x128, 0xF, 0xF, true);
    v += __int_as_float(t);   // ror 8
    return v;
}
// Full sum over the 32-lane ns group (all lanes get the result).
__device__ __forceinline__ float ns32_sum(float v) {
    v = row16_sum(v);
    v += __shfl_xor(v, 16);
    return v;
}

__global__ __launch_bounds__(NT, 2) void caps_kernel(
    const float* __restrict__ x,    // [BSZ, 256, 36] fp32
    const float* __restrict__ Wc,   // [5120, 8] fp32
    const float* __restrict__ bc,   // [5120] fp32
    float* __restrict__ out)        // [BSZ, 10, 16] fp32
{
    __shared__ h2 xs[NIC * 4];          // 18432 B: row i=p*32+ns, 8 halfs (b128)
    __shared__ h2 eJ[NOC * 18 * 32];    // 23040 B: e pairs, (j*18+pr)*32+ns
    __shared__ h2 sinvH[18 * 32];       //  2304 B: 1/denom pairs, pr*32+ns
    // total 43776 B -> 2 blocks/CU (grid 512 = 2/CU)

    const int tid = threadIdx.x;
    const float* xb = x + (size_t)blockIdx.x * (C_IN * HW);

    // ---- Stage x -> fp16 LDS row-major (conflict-free; validated R7/R9) ----
    for (int t5 = tid; t5 < 9 * 128; t5 += NT) {
        int p4 = t5 >> 7, c2 = t5 & 127;
        int nsc = c2 >> 2, k2 = c2 & 3;
        const float* s0 = xb + (2 * c2) * HW + p4 * 4;
        float4 a = *(const float4*)s0;
        float4 b = *(const float4*)(s0 + HW);
        xs[((p4 * 4 + 0) * 32 + nsc) * 4 + k2] = __floats2half2_rn(a.x, b.x);
        xs[((p4 * 4 + 1) * 32 + nsc) * 4 + k2] = __floats2half2_rn(a.y, b.y);
        xs[((p4 * 4 + 2) * 32 + nsc) * 4 + k2] = __floats2half2_rn(a.z, b.z);
        xs[((p4 * 4 + 3) * 32 + nsc) * 4 + k2] = __floats2half2_rn(a.w, b.w);
    }

    const int j     = tid >> 6;         // 0..9 (= wave index)
    const int dhalf = (tid >> 5) & 1;   // which 8 of the 16 out-dims
    const int ns    = tid & 31;

    // ---- One-time: W rows (own 8 d x 8 k) fp32 -> 32 h2 regs; bias -> f32 ----
    h2    wreg[32];
    float bcv[8];
    {
        const float* wp = Wc + (size_t)(ns * 160 + j * 16 + dhalf * 8) * 8;
        #pragma unroll
        for (int dd = 0; dd < 8; ++dd) {
            float4 a = *(const float4*)(wp + dd * 8);
            float4 b = *(const float4*)(wp + dd * 8 + 4);
            wreg[dd * 4 + 0] = __floats2half2_rn(a.x, a.y);
            wreg[dd * 4 + 1] = __floats2half2_rn(a.z, a.w);
            wreg[dd * 4 + 2] = __floats2half2_rn(b.x, b.y);
            wreg[dd * 4 + 3] = __floats2half2_rn(b.z, b.w);
        }
        const float* bp = bc + ns * 160 + j * 16 + dhalf * 8;
        float4 b0 = *(const float4*)bp;
        float4 b1 = *(const float4*)(bp + 4);
        bcv[0]=b0.x; bcv[1]=b0.y; bcv[2]=b0.z; bcv[3]=b0.w;
        bcv[4]=b1.x; bcv[5]=b1.y; bcv[6]=b1.z; bcv[7]=b1.w;
    }
    __syncthreads();

    const int q0 = dhalf * 9;   // own p-pairs pr = q0..q0+8
    float ua[9];                // cumulative routing coefficients (f32 canonical)
    h2    ua2[4];               // packed mirror for the fp16 dots
    h2    ereg[9];              // e = exp(b) for own (j, p-pairs), carried E->B

    for (int it = 0; it < ROUTE; ++it) {
        // ---- Phase B: t2[k2] = sum_p c*x2, tc = sum_p c (own 18 p) ----
        h2 t2[4];
        h2 zz = __float2half2_rn(0.f);
        t2[0] = zz; t2[1] = zz; t2[2] = zz; t2[3] = zz;
        float tc = 0.f;
        if (it == 0) {
            #pragma unroll
            for (int q = 0; q < 9; ++q) {
                #pragma unroll
                for (int s = 0; s < 2; ++s) {
                    int row = (2 * (q0 + q) + s) * 32 + ns;
                    uint4 xv = *(const uint4*)&xs[row * 4];
                    t2[0] = __hadd2(t2[0], u2h(xv.x));
                    t2[1] = __hadd2(t2[1], u2h(xv.y));
                    t2[2] = __hadd2(t2[2], u2h(xv.z));
                    t2[3] = __hadd2(t2[3], u2h(xv.w));
                }
            }
            h2 tenth = __float2half2_rn(0.1f);
            #pragma unroll
            for (int k = 0; k < 4; ++k) t2[k] = __hmul2(t2[k], tenth);
            tc = 1.8f;   // per-half; pair merge below doubles to 3.6 (= sum_p 0.1)
        } else {
            #pragma unroll
            for (int q = 0; q < 9; ++q) {
                int pr = q0 + q;
                float2 sv = __half22float2(sinvH[pr * 32 + ns]);
                float2 ef = __half22float2(ereg[q]);
                float c0 = ef.x * sv.x;
                float c1 = ef.y * sv.y;
                tc += c0 + c1;
                h2 c20 = __float2half2_rn(c0);
                h2 c21 = __float2half2_rn(c1);
                {
                    uint4 xv = *(const uint4*)&xs[((2 * pr + 0) * 32 + ns) * 4];
                    t2[0] = __hfma2(c20, u2h(xv.x), t2[0]);
                    t2[1] = __hfma2(c20, u2h(xv.y), t2[1]);
                    t2[2] = __hfma2(c20, u2h(xv.z), t2[2]);
                    t2[3] = __hfma2(c20, u2h(xv.w), t2[3]);
                }
                {
                    uint4 xv = *(const uint4*)&xs[((2 * pr + 1) * 32 + ns) * 4];
                    t2[0] = __hfma2(c21, u2h(xv.x), t2[0]);
                    t2[1] = __hfma2(c21, u2h(xv.y), t2[1]);
                    t2[2] = __hfma2(c21, u2h(xv.z), t2[2]);
                    t2[3] = __hfma2(c21, u2h(xv.w), t2[3]);
                }
            }
        }
        // merge dhalf pair (both halves then hold full-p t)
        #pragma unroll
        for (int k = 0; k < 4; ++k) t2[k] = __hadd2(t2[k], shflx_h2(t2[k], 32));
        tc += __shfl_xor(tc, 32);

        // ---- Phase C: ps[dd] = W·t + bcv*tc (own 8 d); DPP reduce over ns ----
        float ps[8];
        #pragma unroll
        for (int dd = 0; dd < 8; ++dd) {
            h2 a = __hmul2(wreg[dd * 4 + 0], t2[0]);
            a = __hfma2(wreg[dd * 4 + 1], t2[1], a);
            a = __hfma2(wreg[dd * 4 + 2], t2[2], a);
            a = __hfma2(wreg[dd * 4 + 3], t2[3], a);
            float2 f = __half22float2(a);
            ps[dd] = ns32_sum(f.x + f.y + bcv[dd] * tc);
        }
        float ssp = 0.f;
        #pragma unroll
        for (int dd = 0; dd < 8; ++dd) ssp += ps[dd] * ps[dd];
        float ss = ssp + __shfl_xor(ssp, 32);
        float fc = sqrtf(ss) / (1.f + ss);

        if (it == ROUTE - 1) {
            if (ns == 0) {
                float* o = out + (size_t)blockIdx.x * (NOC * OD) + j * OD + dhalf * 8;
                *(float4*)o       = make_float4(ps[0]*fc, ps[1]*fc, ps[2]*fc, ps[3]*fc);
                *(float4*)(o + 4) = make_float4(ps[4]*fc, ps[5]*fc, ps[6]*fc, ps[7]*fc);
            }
            break;
        }

        // ---- Phase D: u2[k2] = sum_d v_d*W2[d,k2] (own 8 d); merge; ua += ----
        h2 u2[4];
        u2[0] = zz; u2[1] = zz; u2[2] = zz; u2[3] = zz;
        float u8 = 0.f;
        #pragma unroll
        for (int dd = 0; dd < 8; ++dd) {
            float vv = ps[dd] * fc;
            h2 v2 = __float2half2_rn(vv);
            u2[0] = __hfma2(v2, wreg[dd * 4 + 0], u2[0]);
            u2[1] = __hfma2(v2, wreg[dd * 4 + 1], u2[1]);
            u2[2] = __hfma2(v2, wreg[dd * 4 + 2], u2[2]);
            u2[3] = __hfma2(v2, wreg[dd * 4 + 3], u2[3]);
            u8 += vv * bcv[dd];
        }
        #pragma unroll
        for (int k = 0; k < 4; ++k) u2[k] = __hadd2(u2[k], shflx_h2(u2[k], 32));
        u8 += __shfl_xor(u8, 32);
        {
            float2 f0 = __half22float2(u2[0]);
            float2 f1 = __half22float2(u2[1]);
            float2 f2 = __half22float2(u2[2]);
            float2 f3 = __half22float2(u2[3]);
            if (it == 0) {
                ua[0]=f0.x; ua[1]=f0.y; ua[2]=f1.x; ua[3]=f1.y;
                ua[4]=f2.x; ua[5]=f2.y; ua[6]=f3.x; ua[7]=f3.y; ua[8]=u8;
            } else {
                ua[0]+=f0.x; ua[1]+=f0.y; ua[2]+=f1.x; ua[3]+=f1.y;
                ua[4]+=f2.x; ua[5]+=f2.y; ua[6]+=f3.x; ua[7]+=f3.y; ua[8]+=u8;
            }
            ua2[0] = __floats2half2_rn(ua[0], ua[1]);
            ua2[1] = __floats2half2_rn(ua[2], ua[3]);
            ua2[2] = __floats2half2_rn(ua[4], ua[5]);
            ua2[3] = __floats2half2_rn(ua[6], ua[7]);
        }

        // ---- Phase E: ereg[q] = exp(ua·(x,1)) pairs; store to eJ for A' ----
        #pragma unroll
        for (int q = 0; q < 9; ++q) {
            int pr = q0 + q;
            float eb[2];
            #pragma unroll
            for (int s = 0; s < 2; ++s) {
                int row = (2 * pr + s) * 32 + ns;
                uint4 xv = *(const uint4*)&xs[row * 4];
                h2 a = __hmul2(ua2[0], u2h(xv.x));
                a = __hfma2(ua2[1], u2h(xv.y), a);
                a = __hfma2(ua2[2], u2h(xv.z), a);
                a = __hfma2(ua2[3], u2h(xv.w), a);
                float2 af = __half22float2(a);
                eb[s] = __expf(ua[8] + af.x + af.y);
            }
            ereg[q] = __floats2half2_rn(eb[0], eb[1]);
            eJ[(j * 18 + pr) * 32 + ns] = ereg[q];
        }
        __syncthreads();

        // ---- Phase A': sinvH = 1/sum_j e (576 pair-tasks, stride-1 banks) ----
        if (tid < 576) {
            int pr = tid >> 5, a = tid & 31;
            h2 s2 = eJ[pr * 32 + a];
            #pragma unroll
            for (int jj = 1; jj < NOC; ++jj)
                s2 = __hadd2(s2, eJ[(jj * 18 + pr) * 32 + a]);
            float2 sf = __half22float2(s2);
            sinvH[pr * 32 + a] =
                __floats2half2_rn(__frcp_rn(sf.x), __frcp_rn(sf.y));
        }
        __syncthreads();
    }
}

extern "C" void kernel_launch(void* const* d_in, const int* in_sizes, int n_in,
                              void* d_out, int out_size, void* d_ws, size_t ws_size,
                              hipStream_t stream) {
    const float* x  = (const float*)d_in[0];
    // d_in[1] = target (int32) — unused in forward
    const float* Wc = (const float*)d_in[2];
    const float* bc = (const float*)d_in[3];
    float* out = (float*)d_out;

    caps_kernel<<<dim3(BSZ), dim3(NT), 0, stream>>>(x, Wc, bc, out);
}